// Round 1
// baseline (1072.570 us; speedup 1.0000x reference)
//
#include <hip/hip_runtime.h>

#define N_NODES 100000
#define N_EDGES 1600000
#define NFEAT 128
#define NHID 64
#define NCLASS 40

// ---------------- degree ----------------
__global__ void deg_kernel(const int* __restrict__ src, int* __restrict__ deg) {
    int i = blockIdx.x * blockDim.x + threadIdx.x;
    if (i < N_EDGES) atomicAdd(&deg[src[i]], 1);
}

__global__ void dinv_kernel(const int* __restrict__ deg, float* __restrict__ dinv) {
    int i = blockIdx.x * blockDim.x + threadIdx.x;
    if (i < N_NODES) dinv[i] = rsqrtf((float)(deg[i] + 1));  // +1 = self loop
}

// ---------------- layer 1 GEMM: h = x @ W1^T + b1 ----------------
// block = 256 threads, handles 16 rows x 64 cols. W1 transposed into LDS as [k][col].
__global__ __launch_bounds__(256) void gemm1_kernel(const float* __restrict__ x,
                                                    const float* __restrict__ W1,
                                                    const float* __restrict__ b1,
                                                    float* __restrict__ h) {
    __shared__ float Wt[NFEAT * NHID];  // 8192 floats = 32 KB, [k*NHID + col]
    int tid = threadIdx.x;
    for (int idx = tid; idx < NFEAT * NHID; idx += 256) {
        int col = idx / NFEAT, k = idx % NFEAT;
        Wt[k * NHID + col] = W1[idx];
    }
    __syncthreads();
    int col = tid & 63;
    int rg  = tid >> 6;
    int row0 = blockIdx.x * 16 + rg * 4;   // N_NODES = 6250*16, exact
    const float* x0 = x + (size_t)row0 * NFEAT;
    float acc0 = 0.f, acc1 = 0.f, acc2 = 0.f, acc3 = 0.f;
    #pragma unroll 8
    for (int k = 0; k < NFEAT; ++k) {
        float w = Wt[k * NHID + col];
        acc0 += x0[k] * w;
        acc1 += x0[NFEAT + k] * w;
        acc2 += x0[2 * NFEAT + k] * w;
        acc3 += x0[3 * NFEAT + k] * w;
    }
    float bb = b1[col];
    h[(size_t)(row0 + 0) * NHID + col] = acc0 + bb;
    h[(size_t)(row0 + 1) * NHID + col] = acc1 + bb;
    h[(size_t)(row0 + 2) * NHID + col] = acc2 + bb;
    h[(size_t)(row0 + 3) * NHID + col] = acc3 + bb;
}

// ---------------- scatter layer 1: agg1[dst] += norm * h[src], 64 feats ----------------
__global__ __launch_bounds__(256) void scatter1_kernel(const int* __restrict__ src,
                                                       const int* __restrict__ dst,
                                                       const float* __restrict__ dinv,
                                                       const float* __restrict__ h,
                                                       float* __restrict__ agg) {
    long long i = (long long)blockIdx.x * blockDim.x + threadIdx.x;
    int e = (int)(i >> 6);
    int f = (int)(i & 63);
    if (e >= N_EDGES + N_NODES) return;
    int s, d; float nrm;
    if (e < N_EDGES) {
        s = src[e]; d = dst[e];
        nrm = dinv[s] * dinv[d];
    } else {
        s = d = e - N_EDGES;          // self loop
        float v = dinv[s];
        nrm = v * v;
    }
    atomicAdd(&agg[(size_t)d * NHID + f], nrm * h[(size_t)s * NHID + f]);
}

// ---------------- layer 2 GEMM: h2 = relu(agg1) @ W2^T + b2 ----------------
__global__ __launch_bounds__(256) void gemm2_kernel(const float* __restrict__ agg1,
                                                    const float* __restrict__ W2,
                                                    const float* __restrict__ b2,
                                                    float* __restrict__ h2) {
    __shared__ float Wl[NCLASS * NHID];  // 2560 floats = 10 KB
    for (int idx = threadIdx.x; idx < NCLASS * NHID; idx += 256) Wl[idx] = W2[idx];
    __syncthreads();
    int i = blockIdx.x * 256 + threadIdx.x;
    if (i >= N_NODES * NCLASS) return;
    int row = i / NCLASS, col = i - row * NCLASS;
    const float* a = agg1 + (size_t)row * NHID;
    const float* w = Wl + col * NHID;
    float acc = b2[col];
    #pragma unroll 8
    for (int k = 0; k < NHID; ++k) acc += fmaxf(a[k], 0.f) * w[k];
    h2[i] = acc;
}

// ---------------- scatter layer 2: out[dst] += norm * h2[src], 40 feats ----------------
__global__ __launch_bounds__(256) void scatter2_kernel(const int* __restrict__ src,
                                                       const int* __restrict__ dst,
                                                       const float* __restrict__ dinv,
                                                       const float* __restrict__ h2,
                                                       float* __restrict__ out) {
    long long i = (long long)blockIdx.x * blockDim.x + threadIdx.x;
    int e = (int)(i >> 6);
    int f = (int)(i & 63);
    if (e >= N_EDGES + N_NODES) return;
    if (f >= NCLASS) return;
    int s, d; float nrm;
    if (e < N_EDGES) {
        s = src[e]; d = dst[e];
        nrm = dinv[s] * dinv[d];
    } else {
        s = d = e - N_EDGES;
        float v = dinv[s];
        nrm = v * v;
    }
    atomicAdd(&out[(size_t)d * NCLASS + f], nrm * h2[(size_t)s * NCLASS + f]);
}

// ---------------- log_softmax in place, one thread per row ----------------
__global__ __launch_bounds__(256) void lsm_kernel(float* __restrict__ out) {
    int row = blockIdx.x * blockDim.x + threadIdx.x;
    if (row >= N_NODES) return;
    float v[NCLASS];
    float4* p = (float4*)(out + (size_t)row * NCLASS);  // 160 B row, 16B aligned
    float m = -INFINITY;
    #pragma unroll
    for (int j = 0; j < NCLASS / 4; ++j) {
        float4 t = p[j];
        v[4 * j + 0] = t.x; v[4 * j + 1] = t.y;
        v[4 * j + 2] = t.z; v[4 * j + 3] = t.w;
        m = fmaxf(m, fmaxf(fmaxf(t.x, t.y), fmaxf(t.z, t.w)));
    }
    float sum = 0.f;
    #pragma unroll
    for (int c = 0; c < NCLASS; ++c) sum += __expf(v[c] - m);
    float lse = m + logf(sum);
    #pragma unroll
    for (int j = 0; j < NCLASS / 4; ++j) {
        float4 t;
        t.x = v[4 * j + 0] - lse; t.y = v[4 * j + 1] - lse;
        t.z = v[4 * j + 2] - lse; t.w = v[4 * j + 3] - lse;
        p[j] = t;
    }
}

extern "C" void kernel_launch(void* const* d_in, const int* in_sizes, int n_in,
                              void* d_out, int out_size, void* d_ws, size_t ws_size,
                              hipStream_t stream) {
    const float* x  = (const float*)d_in[0];
    const float* W1 = (const float*)d_in[1];
    const float* b1 = (const float*)d_in[2];
    const float* W2 = (const float*)d_in[3];
    const float* b2 = (const float*)d_in[4];
    const int*   ei = (const int*)d_in[5];
    const int* src = ei;              // edge_index[0]
    const int* dst = ei + N_EDGES;    // edge_index[1]
    float* out = (float*)d_out;

    char* ws = (char*)d_ws;
    int*   deg  = (int*)ws;   ws += (size_t)N_NODES * sizeof(int);
    float* dinv = (float*)ws; ws += (size_t)N_NODES * sizeof(float);
    float* h    = (float*)ws; ws += (size_t)N_NODES * NHID * sizeof(float);
    float* agg1 = (float*)ws; ws += (size_t)N_NODES * NHID * sizeof(float);
    float* h2   = h;  // reuse: h dead after scatter1

    hipMemsetAsync(deg, 0, (size_t)N_NODES * sizeof(int), stream);
    hipMemsetAsync(agg1, 0, (size_t)N_NODES * NHID * sizeof(float), stream);
    hipMemsetAsync(d_out, 0, (size_t)N_NODES * NCLASS * sizeof(float), stream);

    deg_kernel<<<(N_EDGES + 255) / 256, 256, 0, stream>>>(src, deg);
    dinv_kernel<<<(N_NODES + 255) / 256, 256, 0, stream>>>(deg, dinv);
    gemm1_kernel<<<N_NODES / 16, 256, 0, stream>>>(x, W1, b1, h);

    long long work = (long long)(N_EDGES + N_NODES) * 64;
    int nblk = (int)((work + 255) / 256);
    scatter1_kernel<<<nblk, 256, 0, stream>>>(src, dst, dinv, h, agg1);

    gemm2_kernel<<<(N_NODES * NCLASS + 255) / 256, 256, 0, stream>>>(agg1, W2, b2, h2);
    scatter2_kernel<<<nblk, 256, 0, stream>>>(src, dst, dinv, h2, out);
    lsm_kernel<<<(N_NODES + 255) / 256, 256, 0, stream>>>(out);
}

// Round 2
// 778.419 us; speedup vs baseline: 1.3779x; 1.3779x over previous
//
#include <hip/hip_runtime.h>

#define N_NODES 100000
#define N_EDGES 1600000
#define NFEAT 128
#define NHID 64
#define NCLASS 40
#define SCAN_B 256

// ---------------- count: deg over src (for norm), cnt over dst (for CSR) ----------------
__global__ void count_kernel(const int* __restrict__ src, const int* __restrict__ dst,
                             int* __restrict__ deg_src, int* __restrict__ cnt_dst) {
    int i = blockIdx.x * blockDim.x + threadIdx.x;
    if (i < N_EDGES) {
        atomicAdd(&deg_src[src[i]], 1);
        atomicAdd(&cnt_dst[dst[i]], 1);
    }
}

__global__ void dinv_kernel(const int* __restrict__ deg, float* __restrict__ dinv) {
    int i = blockIdx.x * blockDim.x + threadIdx.x;
    if (i < N_NODES) dinv[i] = rsqrtf((float)(deg[i] + 1));  // +1 = self loop
}

// ---------------- 3-kernel exclusive scan over cnt_dst ----------------
__global__ void scan1_kernel(const int* __restrict__ cnt, int* __restrict__ partial,
                             int* __restrict__ bsums) {
    __shared__ int tmp[SCAN_B];
    int gid = blockIdx.x * SCAN_B + threadIdx.x;
    int v = (gid < N_NODES) ? cnt[gid] : 0;
    tmp[threadIdx.x] = v;
    __syncthreads();
    for (int off = 1; off < SCAN_B; off <<= 1) {
        int t = (threadIdx.x >= off) ? tmp[threadIdx.x - off] : 0;
        __syncthreads();
        tmp[threadIdx.x] += t;
        __syncthreads();
    }
    if (gid < N_NODES) partial[gid] = tmp[threadIdx.x] - v;  // exclusive within block
    if (threadIdx.x == SCAN_B - 1) bsums[blockIdx.x] = tmp[threadIdx.x];
}

__global__ void scan2_kernel(int* __restrict__ bsums, int nb) {
    __shared__ int tmp[512];
    int v = (threadIdx.x < nb) ? bsums[threadIdx.x] : 0;
    tmp[threadIdx.x] = v;
    __syncthreads();
    for (int off = 1; off < 512; off <<= 1) {
        int t = (threadIdx.x >= off) ? tmp[threadIdx.x - off] : 0;
        __syncthreads();
        tmp[threadIdx.x] += t;
        __syncthreads();
    }
    if (threadIdx.x < nb) bsums[threadIdx.x] = tmp[threadIdx.x] - v;  // exclusive
}

__global__ void scan3_kernel(const int* __restrict__ partial, const int* __restrict__ bsums,
                             int* __restrict__ offs, int* __restrict__ curs) {
    int gid = blockIdx.x * 256 + threadIdx.x;
    if (gid < N_NODES) {
        int o = partial[gid] + bsums[gid >> 8];
        offs[gid] = o;
        curs[gid] = o;
    }
}

// ---------------- fill CSR: edges[pos] = {src, norm} ----------------
__global__ void fill_kernel(const int* __restrict__ src, const int* __restrict__ dst,
                            const float* __restrict__ dinv, int* __restrict__ curs,
                            int2* __restrict__ edges) {
    int i = blockIdx.x * blockDim.x + threadIdx.x;
    if (i < N_EDGES) {
        int s = src[i], d = dst[i];
        int pos = atomicAdd(&curs[d], 1);
        float nrm = dinv[s] * dinv[d];
        edges[pos] = make_int2(s, __float_as_int(nrm));
    }
}

// ---------------- layer 1 GEMM: h = x @ W1^T + b1 ----------------
__global__ __launch_bounds__(256) void gemm1_kernel(const float* __restrict__ x,
                                                    const float* __restrict__ W1,
                                                    const float* __restrict__ b1,
                                                    float* __restrict__ h) {
    __shared__ float Wt[NFEAT * NHID];  // [k*NHID + col], 32 KB
    int tid = threadIdx.x;
    for (int idx = tid; idx < NFEAT * NHID; idx += 256) {
        int col = idx / NFEAT, k = idx % NFEAT;
        Wt[k * NHID + col] = W1[idx];
    }
    __syncthreads();
    int col = tid & 63;
    int rg  = tid >> 6;
    int row0 = blockIdx.x * 16 + rg * 4;  // N_NODES = 6250*16
    const float* x0 = x + (size_t)row0 * NFEAT;
    float acc0 = 0.f, acc1 = 0.f, acc2 = 0.f, acc3 = 0.f;
    #pragma unroll 8
    for (int k = 0; k < NFEAT; ++k) {
        float w = Wt[k * NHID + col];
        acc0 += x0[k] * w;
        acc1 += x0[NFEAT + k] * w;
        acc2 += x0[2 * NFEAT + k] * w;
        acc3 += x0[3 * NFEAT + k] * w;
    }
    float bb = b1[col];
    h[(size_t)(row0 + 0) * NHID + col] = acc0 + bb;
    h[(size_t)(row0 + 1) * NHID + col] = acc1 + bb;
    h[(size_t)(row0 + 2) * NHID + col] = acc2 + bb;
    h[(size_t)(row0 + 3) * NHID + col] = acc3 + bb;
}

// ---------------- pull-aggregation layer 1: one wave per dst node, lane = feature ----------------
__global__ __launch_bounds__(256) void agg1_kernel(const int* __restrict__ offs,
                                                   const int* __restrict__ cnt,
                                                   const float* __restrict__ dinv,
                                                   const int2* __restrict__ edges,
                                                   const float* __restrict__ h,
                                                   float* __restrict__ agg) {
    int wid = (blockIdx.x * 256 + threadIdx.x) >> 6;
    int lane = threadIdx.x & 63;
    if (wid >= N_NODES) return;
    int start = offs[wid], n = cnt[wid];
    float di = dinv[wid];
    float acc = di * di * h[(size_t)wid * NHID + lane];  // self loop
    for (int j = 0; j < n; ++j) {
        int2 e = edges[start + j];  // wave-uniform address -> broadcast
        acc += __int_as_float(e.y) * h[(size_t)e.x * NHID + lane];
    }
    agg[(size_t)wid * NHID + lane] = acc;
}

// ---------------- layer 2 GEMM: h2 = relu(agg1) @ W2^T + b2 ----------------
__global__ __launch_bounds__(256) void gemm2_kernel(const float* __restrict__ agg1,
                                                    const float* __restrict__ W2,
                                                    const float* __restrict__ b2,
                                                    float* __restrict__ h2) {
    __shared__ float Wl[NCLASS * NHID];
    for (int idx = threadIdx.x; idx < NCLASS * NHID; idx += 256) Wl[idx] = W2[idx];
    __syncthreads();
    int i = blockIdx.x * 256 + threadIdx.x;
    if (i >= N_NODES * NCLASS) return;
    int row = i / NCLASS, col = i - row * NCLASS;
    const float* a = agg1 + (size_t)row * NHID;
    const float* w = Wl + col * NHID;
    float acc = b2[col];
    #pragma unroll 8
    for (int k = 0; k < NHID; ++k) acc += fmaxf(a[k], 0.f) * w[k];
    h2[i] = acc;
}

// ---------------- pull-aggregation layer 2 + fused log_softmax ----------------
__global__ __launch_bounds__(256) void agg2_kernel(const int* __restrict__ offs,
                                                   const int* __restrict__ cnt,
                                                   const float* __restrict__ dinv,
                                                   const int2* __restrict__ edges,
                                                   const float* __restrict__ h2,
                                                   float* __restrict__ out) {
    int wid = (blockIdx.x * 256 + threadIdx.x) >> 6;
    int lane = threadIdx.x & 63;
    if (wid >= N_NODES) return;
    int start = offs[wid], n = cnt[wid];
    float di = dinv[wid];
    bool act = lane < NCLASS;
    size_t selfbase = (size_t)wid * NCLASS;
    float acc = act ? di * di * h2[selfbase + lane] : 0.f;
    for (int j = 0; j < n; ++j) {
        int2 e = edges[start + j];
        if (act) acc += __int_as_float(e.y) * h2[(size_t)e.x * NCLASS + lane];
    }
    // log_softmax across lanes 0..39
    float m = act ? acc : -INFINITY;
    #pragma unroll
    for (int o = 32; o > 0; o >>= 1) m = fmaxf(m, __shfl_xor(m, o));
    float ex = act ? __expf(acc - m) : 0.f;
    float s = ex;
    #pragma unroll
    for (int o = 32; o > 0; o >>= 1) s += __shfl_xor(s, o);
    if (act) out[selfbase + lane] = acc - m - logf(s);
}

extern "C" void kernel_launch(void* const* d_in, const int* in_sizes, int n_in,
                              void* d_out, int out_size, void* d_ws, size_t ws_size,
                              hipStream_t stream) {
    const float* x  = (const float*)d_in[0];
    const float* W1 = (const float*)d_in[1];
    const float* b1 = (const float*)d_in[2];
    const float* W2 = (const float*)d_in[3];
    const float* b2 = (const float*)d_in[4];
    const int*   ei = (const int*)d_in[5];
    const int* src = ei;
    const int* dst = ei + N_EDGES;
    float* out = (float*)d_out;

    char* ws = (char*)d_ws;
    int*   deg_src = (int*)ws;   ws += (size_t)N_NODES * sizeof(int);
    int*   cnt_dst = (int*)ws;   ws += (size_t)N_NODES * sizeof(int);
    int*   offs    = (int*)ws;   ws += (size_t)N_NODES * sizeof(int);
    int*   curs    = (int*)ws;   ws += (size_t)N_NODES * sizeof(int);
    int*   partial = (int*)ws;   ws += (size_t)N_NODES * sizeof(int);
    int*   bsums   = (int*)ws;   ws += 512 * sizeof(int);
    float* dinv    = (float*)ws; ws += (size_t)N_NODES * sizeof(float);
    int2*  edges   = (int2*)ws;  ws += (size_t)N_EDGES * sizeof(int2);
    float* h       = (float*)ws; ws += (size_t)N_NODES * NHID * sizeof(float);
    float* agg1    = (float*)ws; ws += (size_t)N_NODES * NHID * sizeof(float);
    float* h2      = h;  // reuse: h dead once gemm2 starts (agg1 complete)

    hipMemsetAsync(deg_src, 0, (size_t)N_NODES * sizeof(int), stream);
    hipMemsetAsync(cnt_dst, 0, (size_t)N_NODES * sizeof(int), stream);

    count_kernel<<<(N_EDGES + 255) / 256, 256, 0, stream>>>(src, dst, deg_src, cnt_dst);
    dinv_kernel<<<(N_NODES + 255) / 256, 256, 0, stream>>>(deg_src, dinv);

    int nsb = (N_NODES + SCAN_B - 1) / SCAN_B;  // 391 <= 512
    scan1_kernel<<<nsb, SCAN_B, 0, stream>>>(cnt_dst, partial, bsums);
    scan2_kernel<<<1, 512, 0, stream>>>(bsums, nsb);
    scan3_kernel<<<(N_NODES + 255) / 256, 256, 0, stream>>>(partial, bsums, offs, curs);

    fill_kernel<<<(N_EDGES + 255) / 256, 256, 0, stream>>>(src, dst, dinv, curs, edges);

    gemm1_kernel<<<N_NODES / 16, 256, 0, stream>>>(x, W1, b1, h);

    int nwblk = (N_NODES * 64 + 255) / 256;  // one wave per node
    agg1_kernel<<<nwblk, 256, 0, stream>>>(offs, cnt_dst, dinv, edges, h, agg1);
    gemm2_kernel<<<(N_NODES * NCLASS + 255) / 256, 256, 0, stream>>>(agg1, W2, b2, h2);
    agg2_kernel<<<nwblk, 256, 0, stream>>>(offs, cnt_dst, dinv, edges, h2, out);
}

// Round 3
// 518.066 us; speedup vs baseline: 2.0703x; 1.5025x over previous
//
#include <hip/hip_runtime.h>
#include <hip/hip_fp16.h>

#define N_NODES 100000
#define N_EDGES 1600000
#define NFEAT 128
#define NHID 64
#define NCLASS 40
#define SCAN_B 256

// ---------------- count: deg over src (for norm), cnt over dst (for CSR) ----------------
__global__ void count_kernel(const int* __restrict__ src, const int* __restrict__ dst,
                             int* __restrict__ deg_src, int* __restrict__ cnt_dst) {
    int i = blockIdx.x * blockDim.x + threadIdx.x;
    if (i < N_EDGES) {
        atomicAdd(&deg_src[src[i]], 1);
        atomicAdd(&cnt_dst[dst[i]], 1);
    }
}

__global__ void dinv_kernel(const int* __restrict__ deg, float* __restrict__ dinv) {
    int i = blockIdx.x * blockDim.x + threadIdx.x;
    if (i < N_NODES) dinv[i] = rsqrtf((float)(deg[i] + 1));  // +1 = self loop
}

// ---------------- 3-kernel exclusive scan over cnt_dst ----------------
__global__ void scan1_kernel(const int* __restrict__ cnt, int* __restrict__ partial,
                             int* __restrict__ bsums) {
    __shared__ int tmp[SCAN_B];
    int gid = blockIdx.x * SCAN_B + threadIdx.x;
    int v = (gid < N_NODES) ? cnt[gid] : 0;
    tmp[threadIdx.x] = v;
    __syncthreads();
    for (int off = 1; off < SCAN_B; off <<= 1) {
        int t = (threadIdx.x >= off) ? tmp[threadIdx.x - off] : 0;
        __syncthreads();
        tmp[threadIdx.x] += t;
        __syncthreads();
    }
    if (gid < N_NODES) partial[gid] = tmp[threadIdx.x] - v;  // exclusive within block
    if (threadIdx.x == SCAN_B - 1) bsums[blockIdx.x] = tmp[threadIdx.x];
}

__global__ void scan2_kernel(int* __restrict__ bsums, int nb) {
    __shared__ int tmp[512];
    int v = (threadIdx.x < nb) ? bsums[threadIdx.x] : 0;
    tmp[threadIdx.x] = v;
    __syncthreads();
    for (int off = 1; off < 512; off <<= 1) {
        int t = (threadIdx.x >= off) ? tmp[threadIdx.x - off] : 0;
        __syncthreads();
        tmp[threadIdx.x] += t;
        __syncthreads();
    }
    if (threadIdx.x < nb) bsums[threadIdx.x] = tmp[threadIdx.x] - v;  // exclusive
}

__global__ void scan3_kernel(const int* __restrict__ partial, const int* __restrict__ bsums,
                             int* __restrict__ offs, int* __restrict__ curs) {
    int gid = blockIdx.x * 256 + threadIdx.x;
    if (gid < N_NODES) {
        int o = partial[gid] + bsums[gid >> 8];
        offs[gid] = o;
        curs[gid] = o;
    }
}

// ---------------- fill CSR: edges[pos] = {src, norm} ----------------
__global__ void fill_kernel(const int* __restrict__ src, const int* __restrict__ dst,
                            const float* __restrict__ dinv, int* __restrict__ curs,
                            int2* __restrict__ edges) {
    int i = blockIdx.x * blockDim.x + threadIdx.x;
    if (i < N_EDGES) {
        int s = src[i], d = dst[i];
        int pos = atomicAdd(&curs[d], 1);
        float nrm = dinv[s] * dinv[d];
        edges[pos] = make_int2(s, __float_as_int(nrm));
    }
}

// ---------------- layer 1 GEMM: h = fp16(x @ W1^T + b1) ----------------
__global__ __launch_bounds__(256) void gemm1_kernel(const float* __restrict__ x,
                                                    const float* __restrict__ W1,
                                                    const float* __restrict__ b1,
                                                    __half* __restrict__ h) {
    __shared__ float Wt[NFEAT * NHID];  // [k*NHID + col], 32 KB
    int tid = threadIdx.x;
    for (int idx = tid; idx < NFEAT * NHID; idx += 256) {
        int col = idx / NFEAT, k = idx % NFEAT;
        Wt[k * NHID + col] = W1[idx];
    }
    __syncthreads();
    int col = tid & 63;
    int rg  = tid >> 6;
    int row0 = blockIdx.x * 16 + rg * 4;  // N_NODES = 6250*16
    const float4* x4 = (const float4*)(x + (size_t)row0 * NFEAT);
    float acc0 = 0.f, acc1 = 0.f, acc2 = 0.f, acc3 = 0.f;
    #pragma unroll 4
    for (int k4 = 0; k4 < NFEAT / 4; ++k4) {
        float4 a0 = x4[k4];
        float4 a1 = x4[32 + k4];
        float4 a2 = x4[64 + k4];
        float4 a3 = x4[96 + k4];
        float w0 = Wt[(4 * k4 + 0) * NHID + col];
        float w1 = Wt[(4 * k4 + 1) * NHID + col];
        float w2 = Wt[(4 * k4 + 2) * NHID + col];
        float w3 = Wt[(4 * k4 + 3) * NHID + col];
        acc0 += a0.x * w0 + a0.y * w1 + a0.z * w2 + a0.w * w3;
        acc1 += a1.x * w0 + a1.y * w1 + a1.z * w2 + a1.w * w3;
        acc2 += a2.x * w0 + a2.y * w1 + a2.z * w2 + a2.w * w3;
        acc3 += a3.x * w0 + a3.y * w1 + a3.z * w2 + a3.w * w3;
    }
    float bb = b1[col];
    h[(size_t)(row0 + 0) * NHID + col] = __float2half(acc0 + bb);
    h[(size_t)(row0 + 1) * NHID + col] = __float2half(acc1 + bb);
    h[(size_t)(row0 + 2) * NHID + col] = __float2half(acc2 + bb);
    h[(size_t)(row0 + 3) * NHID + col] = __float2half(acc3 + bb);
}

// ---------------- pull-aggregation layer 1: wave/node, two half-waves split the bucket.
// Writes z = fp16(relu(agg)) directly. ----------------
__global__ __launch_bounds__(256) void agg1_kernel(const int* __restrict__ offs,
                                                   const int* __restrict__ cnt,
                                                   const float* __restrict__ dinv,
                                                   const int2* __restrict__ edges,
                                                   const __half* __restrict__ h,
                                                   __half* __restrict__ z) {
    int wid = (blockIdx.x * 256 + threadIdx.x) >> 6;
    if (wid >= N_NODES) return;
    int lane = threadIdx.x & 63;
    int hw = lane >> 5;   // half-wave id
    int fl = lane & 31;   // feature pair: features 2*fl, 2*fl+1
    int start = offs[wid], n = cnt[wid];
    int c0 = (n + 1) >> 1;
    int myn = hw ? (n - c0) : c0;
    const int2* eb = edges + start + (hw ? c0 : 0);
    float ax = 0.f, ay = 0.f;
    int j = 0;
    for (; j + 4 <= myn; j += 4) {     // 4 gathers in flight per half-wave
        int2 e0 = eb[j], e1 = eb[j + 1], e2 = eb[j + 2], e3 = eb[j + 3];
        float2 f0 = __half22float2(*(const __half2*)(h + ((size_t)e0.x << 6) + 2 * fl));
        float2 f1 = __half22float2(*(const __half2*)(h + ((size_t)e1.x << 6) + 2 * fl));
        float2 f2 = __half22float2(*(const __half2*)(h + ((size_t)e2.x << 6) + 2 * fl));
        float2 f3 = __half22float2(*(const __half2*)(h + ((size_t)e3.x << 6) + 2 * fl));
        float w0 = __int_as_float(e0.y), w1 = __int_as_float(e1.y);
        float w2 = __int_as_float(e2.y), w3 = __int_as_float(e3.y);
        ax += w0 * f0.x + w1 * f1.x + w2 * f2.x + w3 * f3.x;
        ay += w0 * f0.y + w1 * f1.y + w2 * f2.y + w3 * f3.y;
    }
    for (; j < myn; ++j) {
        int2 e = eb[j];
        float2 f = __half22float2(*(const __half2*)(h + ((size_t)e.x << 6) + 2 * fl));
        float w = __int_as_float(e.y);
        ax += w * f.x;
        ay += w * f.y;
    }
    ax += __shfl_xor(ax, 32);
    ay += __shfl_xor(ay, 32);
    if (hw == 0) {
        float di = dinv[wid];
        float2 f = __half22float2(*(const __half2*)(h + ((size_t)wid << 6) + 2 * fl));
        ax += di * di * f.x;
        ay += di * di * f.y;
        *(__half2*)(z + ((size_t)wid << 6) + 2 * fl) =
            __floats2half2_rn(fmaxf(ax, 0.f), fmaxf(ay, 0.f));
    }
}

// ---------------- layer 2 GEMM: h2 = fp16(z @ W2^T + b2), z already relu'd ----------------
__global__ __launch_bounds__(256) void gemm2_kernel(const __half* __restrict__ z,
                                                    const float* __restrict__ W2,
                                                    const float* __restrict__ b2,
                                                    __half* __restrict__ h2) {
    __shared__ float Wl[NHID * NCLASS];  // [k*NCLASS + col] -> conflict-free
    for (int idx = threadIdx.x; idx < NCLASS * NHID; idx += 256) {
        int c = idx / NHID, k = idx % NHID;
        Wl[k * NCLASS + c] = W2[idx];
    }
    __syncthreads();
    int i = blockIdx.x * 256 + threadIdx.x;
    if (i >= N_NODES * NCLASS) return;
    int row = i / NCLASS, col = i - row * NCLASS;
    const __half2* a = (const __half2*)(z + (size_t)row * NHID);
    float acc = b2[col];
    #pragma unroll 8
    for (int k2 = 0; k2 < NHID / 2; ++k2) {
        float2 f = __half22float2(a[k2]);
        acc += f.x * Wl[(2 * k2) * NCLASS + col] + f.y * Wl[(2 * k2 + 1) * NCLASS + col];
    }
    h2[i] = __float2half(acc);
}

// ---------------- pull-aggregation layer 2 + fused log_softmax ----------------
__global__ __launch_bounds__(256) void agg2_kernel(const int* __restrict__ offs,
                                                   const int* __restrict__ cnt,
                                                   const float* __restrict__ dinv,
                                                   const int2* __restrict__ edges,
                                                   const __half* __restrict__ h2,
                                                   float* __restrict__ out) {
    int wid = (blockIdx.x * 256 + threadIdx.x) >> 6;
    if (wid >= N_NODES) return;
    int lane = threadIdx.x & 63;
    int hw = lane >> 5;
    int fl = lane & 31;          // feature pair: 2*fl, 2*fl+1 (active for fl < 20)
    bool act = fl < NCLASS / 2;
    int start = offs[wid], n = cnt[wid];
    int c0 = (n + 1) >> 1;
    int myn = hw ? (n - c0) : c0;
    const int2* eb = edges + start + (hw ? c0 : 0);
    float ax = 0.f, ay = 0.f;
    int j = 0;
    if (act) {
        for (; j + 4 <= myn; j += 4) {
            int2 e0 = eb[j], e1 = eb[j + 1], e2 = eb[j + 2], e3 = eb[j + 3];
            float2 f0 = __half22float2(*(const __half2*)(h2 + (size_t)e0.x * NCLASS + 2 * fl));
            float2 f1 = __half22float2(*(const __half2*)(h2 + (size_t)e1.x * NCLASS + 2 * fl));
            float2 f2 = __half22float2(*(const __half2*)(h2 + (size_t)e2.x * NCLASS + 2 * fl));
            float2 f3 = __half22float2(*(const __half2*)(h2 + (size_t)e3.x * NCLASS + 2 * fl));
            float w0 = __int_as_float(e0.y), w1 = __int_as_float(e1.y);
            float w2 = __int_as_float(e2.y), w3 = __int_as_float(e3.y);
            ax += w0 * f0.x + w1 * f1.x + w2 * f2.x + w3 * f3.x;
            ay += w0 * f0.y + w1 * f1.y + w2 * f2.y + w3 * f3.y;
        }
        for (; j < myn; ++j) {
            int2 e = eb[j];
            float2 f = __half22float2(*(const __half2*)(h2 + (size_t)e.x * NCLASS + 2 * fl));
            float w = __int_as_float(e.y);
            ax += w * f.x;
            ay += w * f.y;
        }
    }
    ax += __shfl_xor(ax, 32);
    ay += __shfl_xor(ay, 32);
    // self loop (after combine; add once, both halves recompute identically below via hw==0 write)
    float di = dinv[wid];
    if (act) {
        float2 f = __half22float2(*(const __half2*)(h2 + (size_t)wid * NCLASS + 2 * fl));
        ax += di * di * f.x;
        ay += di * di * f.y;
    }
    // log_softmax across the 20 active pairs of each 32-lane half (both halves identical)
    float m = act ? fmaxf(ax, ay) : -INFINITY;
    #pragma unroll
    for (int o = 16; o > 0; o >>= 1) m = fmaxf(m, __shfl_xor(m, o));
    float s = act ? (__expf(ax - m) + __expf(ay - m)) : 0.f;
    #pragma unroll
    for (int o = 16; o > 0; o >>= 1) s += __shfl_xor(s, o);
    if (hw == 0 && act) {
        float lse = m + logf(s);
        *(float2*)(out + (size_t)wid * NCLASS + 2 * fl) = make_float2(ax - lse, ay - lse);
    }
}

extern "C" void kernel_launch(void* const* d_in, const int* in_sizes, int n_in,
                              void* d_out, int out_size, void* d_ws, size_t ws_size,
                              hipStream_t stream) {
    const float* x  = (const float*)d_in[0];
    const float* W1 = (const float*)d_in[1];
    const float* b1 = (const float*)d_in[2];
    const float* W2 = (const float*)d_in[3];
    const float* b2 = (const float*)d_in[4];
    const int*   ei = (const int*)d_in[5];
    const int* src = ei;
    const int* dst = ei + N_EDGES;
    float* out = (float*)d_out;

    char* ws = (char*)d_ws;
    int*    deg_src = (int*)ws;    ws += (size_t)N_NODES * sizeof(int);
    int*    cnt_dst = (int*)ws;    ws += (size_t)N_NODES * sizeof(int);
    int*    offs    = (int*)ws;    ws += (size_t)N_NODES * sizeof(int);
    int*    curs    = (int*)ws;    ws += (size_t)N_NODES * sizeof(int);
    int*    partial = (int*)ws;    ws += (size_t)N_NODES * sizeof(int);
    int*    bsums   = (int*)ws;    ws += 512 * sizeof(int);
    float*  dinv    = (float*)ws;  ws += (size_t)N_NODES * sizeof(float);
    int2*   edges   = (int2*)ws;   ws += (size_t)N_EDGES * sizeof(int2);
    __half* h       = (__half*)ws; ws += (size_t)N_NODES * NHID * sizeof(__half);
    __half* z       = (__half*)ws; ws += (size_t)N_NODES * NHID * sizeof(__half);
    __half* h2      = (__half*)ws; ws += (size_t)N_NODES * NCLASS * sizeof(__half);

    hipMemsetAsync(deg_src, 0, (size_t)N_NODES * sizeof(int), stream);
    hipMemsetAsync(cnt_dst, 0, (size_t)N_NODES * sizeof(int), stream);

    count_kernel<<<(N_EDGES + 255) / 256, 256, 0, stream>>>(src, dst, deg_src, cnt_dst);
    dinv_kernel<<<(N_NODES + 255) / 256, 256, 0, stream>>>(deg_src, dinv);

    int nsb = (N_NODES + SCAN_B - 1) / SCAN_B;  // 391 <= 512
    scan1_kernel<<<nsb, SCAN_B, 0, stream>>>(cnt_dst, partial, bsums);
    scan2_kernel<<<1, 512, 0, stream>>>(bsums, nsb);
    scan3_kernel<<<(N_NODES + 255) / 256, 256, 0, stream>>>(partial, bsums, offs, curs);

    fill_kernel<<<(N_EDGES + 255) / 256, 256, 0, stream>>>(src, dst, dinv, curs, edges);

    gemm1_kernel<<<N_NODES / 16, 256, 0, stream>>>(x, W1, b1, h);

    int nwblk = (N_NODES * 64 + 255) / 256;  // one wave per node
    agg1_kernel<<<nwblk, 256, 0, stream>>>(offs, cnt_dst, dinv, edges, h, z);
    gemm2_kernel<<<(N_NODES * NCLASS + 255) / 256, 256, 0, stream>>>(z, W2, b2, h2);
    agg2_kernel<<<nwblk, 256, 0, stream>>>(offs, cnt_dst, dinv, edges, h2, out);
}

// Round 4
// 516.942 us; speedup vs baseline: 2.0748x; 1.0022x over previous
//
#include <hip/hip_runtime.h>
#include <hip/hip_fp16.h>

#define N_NODES 100000
#define N_EDGES 1600000
#define NFEAT 128
#define NHID 64
#define NCLASS 40
#define SCAN_B 256
#define WSTRIDE (NHID + 1)   // 65: bank-conflict-free LDS stride for gemm1

// ---------------- count: deg over src (for norm), cnt over dst (for CSR) ----------------
__global__ void count_kernel(const int* __restrict__ src, const int* __restrict__ dst,
                             int* __restrict__ deg_src, int* __restrict__ cnt_dst) {
    int i = blockIdx.x * blockDim.x + threadIdx.x;
    if (i < N_EDGES) {
        atomicAdd(&deg_src[src[i]], 1);
        atomicAdd(&cnt_dst[dst[i]], 1);
    }
}

__global__ void dinv_kernel(const int* __restrict__ deg, float* __restrict__ dinv) {
    int i = blockIdx.x * blockDim.x + threadIdx.x;
    if (i < N_NODES) dinv[i] = rsqrtf((float)(deg[i] + 1));  // +1 = self loop
}

// ---------------- 3-kernel exclusive scan over cnt_dst ----------------
__global__ void scan1_kernel(const int* __restrict__ cnt, int* __restrict__ partial,
                             int* __restrict__ bsums) {
    __shared__ int tmp[SCAN_B];
    int gid = blockIdx.x * SCAN_B + threadIdx.x;
    int v = (gid < N_NODES) ? cnt[gid] : 0;
    tmp[threadIdx.x] = v;
    __syncthreads();
    for (int off = 1; off < SCAN_B; off <<= 1) {
        int t = (threadIdx.x >= off) ? tmp[threadIdx.x - off] : 0;
        __syncthreads();
        tmp[threadIdx.x] += t;
        __syncthreads();
    }
    if (gid < N_NODES) partial[gid] = tmp[threadIdx.x] - v;  // exclusive within block
    if (threadIdx.x == SCAN_B - 1) bsums[blockIdx.x] = tmp[threadIdx.x];
}

__global__ void scan2_kernel(int* __restrict__ bsums, int nb) {
    __shared__ int tmp[512];
    int v = (threadIdx.x < nb) ? bsums[threadIdx.x] : 0;
    tmp[threadIdx.x] = v;
    __syncthreads();
    for (int off = 1; off < 512; off <<= 1) {
        int t = (threadIdx.x >= off) ? tmp[threadIdx.x - off] : 0;
        __syncthreads();
        tmp[threadIdx.x] += t;
        __syncthreads();
    }
    if (threadIdx.x < nb) bsums[threadIdx.x] = tmp[threadIdx.x] - v;  // exclusive
}

__global__ void scan3_kernel(const int* __restrict__ partial, const int* __restrict__ bsums,
                             int* __restrict__ offs, int* __restrict__ curs) {
    int gid = blockIdx.x * 256 + threadIdx.x;
    if (gid < N_NODES) {
        int o = partial[gid] + bsums[gid >> 8];
        offs[gid] = o;
        curs[gid] = o;
    }
}

// ---------------- fill CSR: edges[pos] = {src, norm} ----------------
__global__ void fill_kernel(const int* __restrict__ src, const int* __restrict__ dst,
                            const float* __restrict__ dinv, int* __restrict__ curs,
                            int2* __restrict__ edges) {
    int i = blockIdx.x * blockDim.x + threadIdx.x;
    if (i < N_EDGES) {
        int s = src[i], d = dst[i];
        int pos = atomicAdd(&curs[d], 1);
        float nrm = dinv[s] * dinv[d];
        edges[pos] = make_int2(s, __float_as_int(nrm));
    }
}

// ---------------- layer 1 GEMM: h = fp16(x @ W1^T + b1) ----------------
__global__ __launch_bounds__(256) void gemm1_kernel(const float* __restrict__ x,
                                                    const float* __restrict__ W1,
                                                    const float* __restrict__ b1,
                                                    __half* __restrict__ h) {
    __shared__ float Wt[NFEAT * WSTRIDE];  // [k*65 + col]: conflict-free write AND read
    int tid = threadIdx.x;
    for (int idx = tid; idx < NFEAT * NHID; idx += 256) {
        int col = idx / NFEAT, k = idx % NFEAT;
        Wt[k * WSTRIDE + col] = W1[idx];
    }
    __syncthreads();
    int col = tid & 63;
    int rg  = tid >> 6;
    int row0 = blockIdx.x * 16 + rg * 4;  // N_NODES = 6250*16
    const float4* x4 = (const float4*)(x + (size_t)row0 * NFEAT);
    float acc0 = 0.f, acc1 = 0.f, acc2 = 0.f, acc3 = 0.f;
    #pragma unroll 4
    for (int k4 = 0; k4 < NFEAT / 4; ++k4) {
        float4 a0 = x4[k4];
        float4 a1 = x4[32 + k4];
        float4 a2 = x4[64 + k4];
        float4 a3 = x4[96 + k4];
        float w0 = Wt[(4 * k4 + 0) * WSTRIDE + col];
        float w1 = Wt[(4 * k4 + 1) * WSTRIDE + col];
        float w2 = Wt[(4 * k4 + 2) * WSTRIDE + col];
        float w3 = Wt[(4 * k4 + 3) * WSTRIDE + col];
        acc0 += a0.x * w0 + a0.y * w1 + a0.z * w2 + a0.w * w3;
        acc1 += a1.x * w0 + a1.y * w1 + a1.z * w2 + a1.w * w3;
        acc2 += a2.x * w0 + a2.y * w1 + a2.z * w2 + a2.w * w3;
        acc3 += a3.x * w0 + a3.y * w1 + a3.z * w2 + a3.w * w3;
    }
    float bb = b1[col];
    h[(size_t)(row0 + 0) * NHID + col] = __float2half(acc0 + bb);
    h[(size_t)(row0 + 1) * NHID + col] = __float2half(acc1 + bb);
    h[(size_t)(row0 + 2) * NHID + col] = __float2half(acc2 + bb);
    h[(size_t)(row0 + 3) * NHID + col] = __float2half(acc3 + bb);
}

// ---------------- pull-aggregation layer 1: wave/node, two half-waves split the bucket.
// Writes z = fp16(relu(agg)) directly. ----------------
__global__ __launch_bounds__(256) void agg1_kernel(const int* __restrict__ offs,
                                                   const int* __restrict__ cnt,
                                                   const float* __restrict__ dinv,
                                                   const int2* __restrict__ edges,
                                                   const __half* __restrict__ h,
                                                   __half* __restrict__ z) {
    int wid = (blockIdx.x * 256 + threadIdx.x) >> 6;
    if (wid >= N_NODES) return;
    int lane = threadIdx.x & 63;
    int hw = lane >> 5;   // half-wave id
    int fl = lane & 31;   // feature pair: features 2*fl, 2*fl+1
    int start = offs[wid], n = cnt[wid];
    int c0 = (n + 1) >> 1;
    int myn = hw ? (n - c0) : c0;
    const int2* eb = edges + start + (hw ? c0 : 0);
    float ax = 0.f, ay = 0.f;
    int j = 0;
    for (; j + 8 <= myn; j += 8) {     // 8 gathers in flight per half-wave
        int2 e0 = eb[j],     e1 = eb[j + 1], e2 = eb[j + 2], e3 = eb[j + 3];
        int2 e4 = eb[j + 4], e5 = eb[j + 5], e6 = eb[j + 6], e7 = eb[j + 7];
        float2 f0 = __half22float2(*(const __half2*)(h + ((size_t)e0.x << 6) + 2 * fl));
        float2 f1 = __half22float2(*(const __half2*)(h + ((size_t)e1.x << 6) + 2 * fl));
        float2 f2 = __half22float2(*(const __half2*)(h + ((size_t)e2.x << 6) + 2 * fl));
        float2 f3 = __half22float2(*(const __half2*)(h + ((size_t)e3.x << 6) + 2 * fl));
        float2 f4 = __half22float2(*(const __half2*)(h + ((size_t)e4.x << 6) + 2 * fl));
        float2 f5 = __half22float2(*(const __half2*)(h + ((size_t)e5.x << 6) + 2 * fl));
        float2 f6 = __half22float2(*(const __half2*)(h + ((size_t)e6.x << 6) + 2 * fl));
        float2 f7 = __half22float2(*(const __half2*)(h + ((size_t)e7.x << 6) + 2 * fl));
        float w0 = __int_as_float(e0.y), w1 = __int_as_float(e1.y);
        float w2 = __int_as_float(e2.y), w3 = __int_as_float(e3.y);
        float w4 = __int_as_float(e4.y), w5 = __int_as_float(e5.y);
        float w6 = __int_as_float(e6.y), w7 = __int_as_float(e7.y);
        ax += w0 * f0.x + w1 * f1.x + w2 * f2.x + w3 * f3.x
            + w4 * f4.x + w5 * f5.x + w6 * f6.x + w7 * f7.x;
        ay += w0 * f0.y + w1 * f1.y + w2 * f2.y + w3 * f3.y
            + w4 * f4.y + w5 * f5.y + w6 * f6.y + w7 * f7.y;
    }
    for (; j < myn; ++j) {
        int2 e = eb[j];
        float2 f = __half22float2(*(const __half2*)(h + ((size_t)e.x << 6) + 2 * fl));
        float w = __int_as_float(e.y);
        ax += w * f.x;
        ay += w * f.y;
    }
    ax += __shfl_xor(ax, 32);
    ay += __shfl_xor(ay, 32);
    if (hw == 0) {
        float di = dinv[wid];
        float2 f = __half22float2(*(const __half2*)(h + ((size_t)wid << 6) + 2 * fl));
        ax += di * di * f.x;
        ay += di * di * f.y;
        *(__half2*)(z + ((size_t)wid << 6) + 2 * fl) =
            __floats2half2_rn(fmaxf(ax, 0.f), fmaxf(ay, 0.f));
    }
}

// ---------------- layer 2 GEMM: h2 = fp16(z @ W2^T + b2), z already relu'd ----------------
__global__ __launch_bounds__(256) void gemm2_kernel(const __half* __restrict__ z,
                                                    const float* __restrict__ W2,
                                                    const float* __restrict__ b2,
                                                    __half* __restrict__ h2) {
    __shared__ float Wl[NHID * NCLASS];  // [k*NCLASS + col]
    for (int idx = threadIdx.x; idx < NCLASS * NHID; idx += 256) {
        int c = idx / NHID, k = idx % NHID;
        Wl[k * NCLASS + c] = W2[idx];
    }
    __syncthreads();
    int i = blockIdx.x * 256 + threadIdx.x;
    if (i >= N_NODES * NCLASS) return;
    int row = i / NCLASS, col = i - row * NCLASS;
    const __half2* a = (const __half2*)(z + (size_t)row * NHID);
    float acc = b2[col];
    #pragma unroll 8
    for (int k2 = 0; k2 < NHID / 2; ++k2) {
        float2 f = __half22float2(a[k2]);
        acc += f.x * Wl[(2 * k2) * NCLASS + col] + f.y * Wl[(2 * k2 + 1) * NCLASS + col];
    }
    h2[i] = __float2half(acc);
}

// ---------------- pull-aggregation layer 2 + fused log_softmax ----------------
__global__ __launch_bounds__(256) void agg2_kernel(const int* __restrict__ offs,
                                                   const int* __restrict__ cnt,
                                                   const float* __restrict__ dinv,
                                                   const int2* __restrict__ edges,
                                                   const __half* __restrict__ h2,
                                                   float* __restrict__ out) {
    int wid = (blockIdx.x * 256 + threadIdx.x) >> 6;
    if (wid >= N_NODES) return;
    int lane = threadIdx.x & 63;
    int hw = lane >> 5;
    int fl = lane & 31;          // feature pair: 2*fl, 2*fl+1 (active for fl < 20)
    bool act = fl < NCLASS / 2;
    int start = offs[wid], n = cnt[wid];
    int c0 = (n + 1) >> 1;
    int myn = hw ? (n - c0) : c0;
    const int2* eb = edges + start + (hw ? c0 : 0);
    float ax = 0.f, ay = 0.f;
    int j = 0;
    if (act) {
        for (; j + 8 <= myn; j += 8) {
            int2 e0 = eb[j],     e1 = eb[j + 1], e2 = eb[j + 2], e3 = eb[j + 3];
            int2 e4 = eb[j + 4], e5 = eb[j + 5], e6 = eb[j + 6], e7 = eb[j + 7];
            float2 f0 = __half22float2(*(const __half2*)(h2 + (size_t)e0.x * NCLASS + 2 * fl));
            float2 f1 = __half22float2(*(const __half2*)(h2 + (size_t)e1.x * NCLASS + 2 * fl));
            float2 f2 = __half22float2(*(const __half2*)(h2 + (size_t)e2.x * NCLASS + 2 * fl));
            float2 f3 = __half22float2(*(const __half2*)(h2 + (size_t)e3.x * NCLASS + 2 * fl));
            float2 f4 = __half22float2(*(const __half2*)(h2 + (size_t)e4.x * NCLASS + 2 * fl));
            float2 f5 = __half22float2(*(const __half2*)(h2 + (size_t)e5.x * NCLASS + 2 * fl));
            float2 f6 = __half22float2(*(const __half2*)(h2 + (size_t)e6.x * NCLASS + 2 * fl));
            float2 f7 = __half22float2(*(const __half2*)(h2 + (size_t)e7.x * NCLASS + 2 * fl));
            float w0 = __int_as_float(e0.y), w1 = __int_as_float(e1.y);
            float w2 = __int_as_float(e2.y), w3 = __int_as_float(e3.y);
            float w4 = __int_as_float(e4.y), w5 = __int_as_float(e5.y);
            float w6 = __int_as_float(e6.y), w7 = __int_as_float(e7.y);
            ax += w0 * f0.x + w1 * f1.x + w2 * f2.x + w3 * f3.x
                + w4 * f4.x + w5 * f5.x + w6 * f6.x + w7 * f7.x;
            ay += w0 * f0.y + w1 * f1.y + w2 * f2.y + w3 * f3.y
                + w4 * f4.y + w5 * f5.y + w6 * f6.y + w7 * f7.y;
        }
        for (; j < myn; ++j) {
            int2 e = eb[j];
            float2 f = __half22float2(*(const __half2*)(h2 + (size_t)e.x * NCLASS + 2 * fl));
            float w = __int_as_float(e.y);
            ax += w * f.x;
            ay += w * f.y;
        }
    }
    ax += __shfl_xor(ax, 32);
    ay += __shfl_xor(ay, 32);
    float di = dinv[wid];
    if (act) {
        float2 f = __half22float2(*(const __half2*)(h2 + (size_t)wid * NCLASS + 2 * fl));
        ax += di * di * f.x;
        ay += di * di * f.y;
    }
    // log_softmax across the 20 active pairs of each 32-lane half (both halves identical)
    float m = act ? fmaxf(ax, ay) : -INFINITY;
    #pragma unroll
    for (int o = 16; o > 0; o >>= 1) m = fmaxf(m, __shfl_xor(m, o));
    float s = act ? (__expf(ax - m) + __expf(ay - m)) : 0.f;
    #pragma unroll
    for (int o = 16; o > 0; o >>= 1) s += __shfl_xor(s, o);
    if (hw == 0 && act) {
        float lse = m + logf(s);
        *(float2*)(out + (size_t)wid * NCLASS + 2 * fl) = make_float2(ax - lse, ay - lse);
    }
}

extern "C" void kernel_launch(void* const* d_in, const int* in_sizes, int n_in,
                              void* d_out, int out_size, void* d_ws, size_t ws_size,
                              hipStream_t stream) {
    const float* x  = (const float*)d_in[0];
    const float* W1 = (const float*)d_in[1];
    const float* b1 = (const float*)d_in[2];
    const float* W2 = (const float*)d_in[3];
    const float* b2 = (const float*)d_in[4];
    const int*   ei = (const int*)d_in[5];
    const int* src = ei;
    const int* dst = ei + N_EDGES;
    float* out = (float*)d_out;

    char* ws = (char*)d_ws;
    int*    deg_src = (int*)ws;    ws += (size_t)N_NODES * sizeof(int);
    int*    cnt_dst = (int*)ws;    ws += (size_t)N_NODES * sizeof(int);
    int*    offs    = (int*)ws;    ws += (size_t)N_NODES * sizeof(int);
    int*    curs    = (int*)ws;    ws += (size_t)N_NODES * sizeof(int);
    int*    partial = (int*)ws;    ws += (size_t)N_NODES * sizeof(int);
    int*    bsums   = (int*)ws;    ws += 512 * sizeof(int);
    float*  dinv    = (float*)ws;  ws += (size_t)N_NODES * sizeof(float);
    int2*   edges   = (int2*)ws;   ws += (size_t)N_EDGES * sizeof(int2);
    __half* h       = (__half*)ws; ws += (size_t)N_NODES * NHID * sizeof(__half);
    __half* z       = (__half*)ws; ws += (size_t)N_NODES * NHID * sizeof(__half);
    __half* h2      = (__half*)ws; ws += (size_t)N_NODES * NCLASS * sizeof(__half);

    hipMemsetAsync(deg_src, 0, (size_t)N_NODES * sizeof(int), stream);
    hipMemsetAsync(cnt_dst, 0, (size_t)N_NODES * sizeof(int), stream);

    count_kernel<<<(N_EDGES + 255) / 256, 256, 0, stream>>>(src, dst, deg_src, cnt_dst);
    dinv_kernel<<<(N_NODES + 255) / 256, 256, 0, stream>>>(deg_src, dinv);

    int nsb = (N_NODES + SCAN_B - 1) / SCAN_B;  // 391 <= 512
    scan1_kernel<<<nsb, SCAN_B, 0, stream>>>(cnt_dst, partial, bsums);
    scan2_kernel<<<1, 512, 0, stream>>>(bsums, nsb);
    scan3_kernel<<<(N_NODES + 255) / 256, 256, 0, stream>>>(partial, bsums, offs, curs);

    fill_kernel<<<(N_EDGES + 255) / 256, 256, 0, stream>>>(src, dst, dinv, curs, edges);

    gemm1_kernel<<<N_NODES / 16, 256, 0, stream>>>(x, W1, b1, h);

    int nwblk = (N_NODES * 64 + 255) / 256;  // one wave per node
    agg1_kernel<<<nwblk, 256, 0, stream>>>(offs, cnt_dst, dinv, edges, h, z);
    gemm2_kernel<<<(N_NODES * NCLASS + 255) / 256, 256, 0, stream>>>(z, W2, b2, h2);
    agg2_kernel<<<nwblk, 256, 0, stream>>>(offs, cnt_dst, dinv, edges, h2, out);
}